// Round 1
// baseline (332.377 us; speedup 1.0000x reference)
//
#include <hip/hip_runtime.h>
#include <stdint.h>

#define NB   128
#define NOUT 1024
#define NIN  1024

// JAX Threefry-2x32-20, key = (0, 42)  [jax.random.key(42)]
// ks = [0, 42, 0^42^0x1BD11BDA = 0x1BD11BF0]
// Partitionable-mode 32-bit bits: out0 ^ out1 of block with counter (hi=0, lo=j)
__device__ __forceinline__ uint32_t tf_bits(uint32_t j) {
  uint32_t x0 = 0u;          // c0 + ks0 = 0 + 0
  uint32_t x1 = j + 42u;     // c1 + ks1
#define TF_RND(r) { x0 += x1; x1 = (x1 << (r)) | (x1 >> (32 - (r))); x1 ^= x0; }
  TF_RND(13) TF_RND(15) TF_RND(26) TF_RND(6)
  x0 += 42u;         x1 += 0x1BD11BF1u;   // ks1, ks2+1
  TF_RND(17) TF_RND(29) TF_RND(16) TF_RND(24)
  x0 += 0x1BD11BF0u; x1 += 2u;            // ks2, ks0+2
  TF_RND(13) TF_RND(15) TF_RND(26) TF_RND(6)
  /* x0 += ks0=0 */  x1 += 45u;           // ks0, ks1+3
  TF_RND(17) TF_RND(29) TF_RND(16) TF_RND(24)
  x0 += 42u;         x1 += 0x1BD11BF4u;   // ks1, ks2+4
  TF_RND(13) TF_RND(15) TF_RND(26) TF_RND(6)
  x0 += 0x1BD11BF0u; x1 += 5u;            // ks2, ks0+5
#undef TF_RND
  return x0 ^ x1;
}

__global__ __launch_bounds__(256) void syn_kernel(
    const float* __restrict__ input, const float* __restrict__ weight,
    const float* __restrict__ bias, const float* __restrict__ x0v,
    const float* __restrict__ dxv, const float* __restrict__ av,
    const float* __restrict__ dv, float* __restrict__ out) {
  const int o = blockIdx.x;
  const int tid = threadIdx.x;
  __shared__ float s_fac[NIN];      // d + a*sigmoid(dx*(w-x0)) for this o-row
  __shared__ uint32_t s_cnt[256];

  // Stage the per-(o,i) synapse factor once per block (coalesced float4 loads).
  {
    const int base = o * NIN + tid * 4;
    float4 w4  = *(const float4*)(weight + base);
    float4 x04 = *(const float4*)(x0v + base);
    float4 dx4 = *(const float4*)(dxv + base);
    float4 a4  = *(const float4*)(av + base);
    float4 d4  = *(const float4*)(dv + base);
    float s0 = d4.x + a4.x / (1.0f + expf(-(dx4.x * (w4.x - x04.x))));
    float s1 = d4.y + a4.y / (1.0f + expf(-(dx4.y * (w4.y - x04.y))));
    float s2 = d4.z + a4.z / (1.0f + expf(-(dx4.z * (w4.z - x04.z))));
    float s3 = d4.w + a4.w / (1.0f + expf(-(dx4.w * (w4.w - x04.w))));
    *(float4*)(s_fac + tid * 4) = make_float4(s0, s1, s2, s3);
  }
  __syncthreads();

  // Lane = batch row (waves 0/2 -> b=0..63, waves 1/3 -> b=64..127),
  // wave pair splits the i-range in halves. No cross-lane reduction needed.
  const int w = tid >> 6;
  const int l = tid & 63;
  const int b = l + ((w & 1) << 6);
  const int h = w >> 1;
  const uint32_t base_j = ((uint32_t)b << 20) | ((uint32_t)o << 10);
  const float* __restrict__ inrow = input + b * NIN;

  uint32_t cnt = 0;
  const int i1 = h * 512 + 512;
  for (int ic = h * 512; ic < i1; ic += 4) {
    float4 in4 = *(const float4*)(inrow + ic);
    float4 s4  = *(const float4*)(s_fac + ic);   // same addr all lanes: broadcast
    float p0 = fminf(fmaxf(in4.x * s4.x, 0.0f), 1.0f);
    float p1 = fminf(fmaxf(in4.y * s4.y, 0.0f), 1.0f);
    float p2 = fminf(fmaxf(in4.z * s4.z, 0.0f), 1.0f);
    float p3 = fminf(fmaxf(in4.w * s4.w, 0.0f), 1.0f);
    const uint32_t j0 = base_j | (uint32_t)ic;
    // 4 independent threefry chains for ILP
    float u0 = __uint_as_float((tf_bits(j0 + 0u) >> 9) | 0x3F800000u) - 1.0f;
    float u1 = __uint_as_float((tf_bits(j0 + 1u) >> 9) | 0x3F800000u) - 1.0f;
    float u2 = __uint_as_float((tf_bits(j0 + 2u) >> 9) | 0x3F800000u) - 1.0f;
    float u3 = __uint_as_float((tf_bits(j0 + 3u) >> 9) | 0x3F800000u) - 1.0f;
    cnt += (u0 < p0);
    cnt += (u1 < p1);
    cnt += (u2 < p2);
    cnt += (u3 < p3);
  }

  s_cnt[h * 128 + b] = cnt;
  __syncthreads();
  // res = mu + ((Yb-mu)/sigma)*sigma + bias == Yb + bias (to fp32 roundoff)
  if (tid < 128) {
    uint32_t c = s_cnt[tid] + s_cnt[128 + tid];
    out[tid * NOUT + o] = (float)c + bias[o];
  }
}

extern "C" void kernel_launch(void* const* d_in, const int* in_sizes, int n_in,
                              void* d_out, int out_size, void* d_ws, size_t ws_size,
                              hipStream_t stream) {
  const float* input  = (const float*)d_in[0];
  const float* weight = (const float*)d_in[1];
  const float* bias   = (const float*)d_in[2];
  const float* x0v    = (const float*)d_in[3];
  const float* dxv    = (const float*)d_in[4];
  const float* av     = (const float*)d_in[5];
  const float* dv     = (const float*)d_in[6];
  syn_kernel<<<NOUT, 256, 0, stream>>>(input, weight, bias, x0v, dxv, av, dv,
                                       (float*)d_out);
}